// Round 20
// baseline (1266.964 us; speedup 1.0000x reference)
//
#include <hip/hip_runtime.h>
#include <hip/hip_bf16.h>

#define B_ 4
#define N_ 4096
#define H_ 1024
#define NH_ 16
#define HD_ 64
#define M_ 256

typedef __attribute__((ext_vector_type(8))) __bf16 bf16x8;
typedef __attribute__((ext_vector_type(4))) float f32x4;
typedef __attribute__((ext_vector_type(4))) unsigned int u32x4;

__device__ __forceinline__ float bf2f(unsigned short u) {
  union { unsigned int i; float f; } x; x.i = ((unsigned int)u) << 16; return x.f;
}
__device__ __forceinline__ unsigned short f2b(float f) {
  __hip_bfloat16 h = __float2bfloat16(f);
  return *(unsigned short*)&h;
}
__device__ __forceinline__ float gelu_f(float x) {
  const float c = 0.7978845608028654f;
  float t = tanhf(c * (x + 0.044715f * x * x * x));
  return 0.5f * x * (1.0f + t);
}
__device__ __forceinline__ bf16x8 ones8() {
  union { unsigned int u[4]; bf16x8 v; } o;
  o.u[0] = 0x3F803F80u; o.u[1] = 0x3F803F80u; o.u[2] = 0x3F803F80u; o.u[3] = 0x3F803F80u;
  return o.v;
}

typedef __attribute__((address_space(3))) unsigned int as3_uint;
typedef const __attribute__((address_space(1))) unsigned int as1_uint;
__device__ __forceinline__ void gload16(const void* g, void* l) {
  __builtin_amdgcn_global_load_lds((as1_uint*)g, (as3_uint*)l, 16, 0, 0);
}

// ---------------------------------------------------------------------------
// Dense bf16 MFMA GEMM, 256x256 tile, BK=64, 8 waves (2Mx4N, 128x64/wave).
// Schedule = r19-verified counted-vmcnt 2-barrier loop (parameter-scaled):
//   STAGE(t+1) [8 gload16] ; vmcnt(8) [own tile-t loads done] ; s_barrier
//   [publish] ; COMPUTE(t) ; s_barrier [buffer free].
// LDS 128KB (2 x (A 32K | B 32K)); C-tile epilogue reuses all 128KB.
// XCD-aware bijective swizzle; setprio around MFMA clusters.
// ---------------------------------------------------------------------------
template<int ACT>
__launch_bounds__(512)
__global__ void gemm256(const unsigned short* __restrict__ A, int lda,
                        const unsigned short* __restrict__ BT,
                        const float* __restrict__ bias,
                        unsigned short* __restrict__ C, int ldc, int K) {
  __shared__ __align__(16) char LDS[131072];

  const int tid = threadIdx.x;
  const int nwg = gridDim.x * gridDim.y;
  const int lin = blockIdx.y * gridDim.x + blockIdx.x;
  const int mm = (lin & 7) * (nwg >> 3) + (lin >> 3);
  const int bx = mm % gridDim.x, by = mm / gridDim.x;
  const int row0 = by * 256;
  const int col0 = bx * 256;

  const int w = tid >> 6, lane = tid & 63;
  const int wm = w >> 2, wn = w & 3;          // 2 x 4 wave grid
  const int ln = lane & 15, hi = lane >> 4;
  const int rswz = (ln & 7) << 4;

  // staging map: entry id = p*512+tid ; row = id>>3 = p*64 + (tid>>3), c = tid&7
  const int srow = tid >> 3;
  const int schunk = ((tid & 7) ^ (srow & 7)) * 8;   // p*64 keeps row&7 invariant
  const unsigned short* Ab = A + (long long)(row0 + srow) * lda + schunk;
  const unsigned short* Bb = BT + (long long)(col0 + srow) * K + schunk;

  f32x4 acc[8][4];
#pragma unroll
  for (int i = 0; i < 8; ++i)
#pragma unroll
    for (int j = 0; j < 4; ++j) acc[i][j] = (f32x4){0.f, 0.f, 0.f, 0.f};

  auto STAGE = [&](int buf, int k0) {
    char* dA = LDS + buf * 65536;
    char* dB = dA + 32768;
#pragma unroll
    for (int p = 0; p < 4; ++p) {
      gload16(Ab + (long long)p * 64 * lda + k0, dA + p * 8192 + tid * 16);
      gload16(Bb + (long long)p * 64 * K + k0, dB + p * 8192 + tid * 16);
    }
  };
  auto COMPUTE = [&](int buf) {
    char* AsB = LDS + buf * 65536;
    char* BsB = AsB + 32768;
#pragma unroll
    for (int kc = 0; kc < 2; ++kc) {
      const int koff = (kc * 64 + hi * 16) ^ rswz;
      bf16x8 av[8], bv[4];
#pragma unroll
      for (int i = 0; i < 8; ++i)
        av[i] = *(bf16x8*)(AsB + (wm * 128 + i * 16 + ln) * 128 + koff);
#pragma unroll
      for (int j = 0; j < 4; ++j)
        bv[j] = *(bf16x8*)(BsB + (wn * 64 + j * 16 + ln) * 128 + koff);
      __builtin_amdgcn_s_setprio(1);
#pragma unroll
      for (int i = 0; i < 8; ++i)
#pragma unroll
        for (int j = 0; j < 4; ++j)
          acc[i][j] = __builtin_amdgcn_mfma_f32_16x16x32_bf16(av[i], bv[j], acc[i][j], 0, 0, 0);
      __builtin_amdgcn_s_setprio(0);
    }
  };

  const int nT = K >> 6;
  STAGE(0, 0);
  int cur = 0;
  for (int t = 0; t < nT; ++t) {
    if (t + 1 < nT) {
      STAGE(cur ^ 1, (t + 1) * 64);
      asm volatile("s_waitcnt vmcnt(8)" ::: "memory");   // own tile-t loads done
    } else {
      asm volatile("s_waitcnt vmcnt(0)" ::: "memory");
    }
    __builtin_amdgcn_sched_barrier(0);
    __builtin_amdgcn_s_barrier();   // publish tile t across waves
    COMPUTE(cur);
    __builtin_amdgcn_s_barrier();   // buffer cur free before next STAGE hits it
    cur ^= 1;
  }

  // epilogue: stage 256x256 bf16 C tile (exactly 128KB) with row-XOR swizzle
  char* SB = LDS;
#pragma unroll
  for (int j = 0; j < 4; ++j) {
    const int lcol = wn * 64 + j * 16 + ln;
    const float bj = bias ? bias[col0 + lcol] : 0.0f;
#pragma unroll
    for (int i = 0; i < 8; ++i) {
      const int rb_ = wm * 128 + i * 16 + hi * 4;
#pragma unroll
      for (int r = 0; r < 4; ++r) {
        float v = acc[i][j][r] + bj;
        if (ACT == 1) v = gelu_f(v);
        const int row = rb_ + r;
        *(unsigned short*)(SB + ((row * 512 + lcol * 2) ^ ((row & 7) << 4))) = f2b(v);
      }
    }
  }
  __syncthreads();
#pragma unroll
  for (int p = 0; p < 16; ++p) {
    const int idx = p * 512 + tid;
    const int row = idx >> 5, seg = idx & 31;
    u32x4 v = *(u32x4*)(SB + ((row * 512 + seg * 16) ^ ((row & 7) << 4)));
    __builtin_nontemporal_store(v, (u32x4*)(C + (long long)(row0 + row) * ldc + col0 + seg * 8));
  }
}

// ---------------------------------------------------------------------------
// Fused K-feature + ctx + ksum (r17 verified).
// ---------------------------------------------------------------------------
__launch_bounds__(256)
__global__ void ctxksum_mfma(const unsigned short* __restrict__ QKV,
                             const unsigned short* __restrict__ pjB,
                             float* __restrict__ ksumP,     // [64z][8s][256]
                             float* __restrict__ ctxP) {    // [64z*8s][16384]
  __shared__ char Kt[2][8192];
  __shared__ char Vt[2][8192];
  __shared__ char Pt[32768];
  __shared__ float rmaxL[4][64];
  __shared__ float ssqL[64];
  const int z = blockIdx.z, b = z >> 4, hh = z & 15;
  const int sp = blockIdx.x;
  const long long n0 = sp * 512;
  const unsigned short* Kg = QKV + (long long)(b * 4096) * 3072 + 1024 + hh * 64;
  const unsigned short* Vg = QKV + (long long)(b * 4096) * 3072 + 2048 + hh * 64;
  const int tid = threadIdx.x;
  const int w = tid >> 6, lane = tid & 63;
  const int ln = lane & 15, hi = lane >> 4;
  const int rswz = (ln & 7) << 4;
  const bf16x8 onesf = ones8();

  f32x4 accC[4][4];
#pragma unroll
  for (int i = 0; i < 4; ++i)
#pragma unroll
    for (int j = 0; j < 4; ++j) accC[i][j] = (f32x4){0.f, 0.f, 0.f, 0.f};
  f32x4 accK[4];
#pragma unroll
  for (int i = 0; i < 4; ++i) accK[i] = (f32x4){0.f, 0.f, 0.f, 0.f};

  const int vn = tid >> 2, vd0 = (tid & 3) * 16;
  ushort4 vr[4];
  auto VLOAD = [&](long long nt) {
    const unsigned short* src = Vg + (nt + vn) * 3072 + vd0;
    vr[0] = *(const ushort4*)src;
    vr[1] = *(const ushort4*)(src + 4);
    vr[2] = *(const ushort4*)(src + 8);
    vr[3] = *(const ushort4*)(src + 12);
  };
  auto VWRITE = [&](int buf) {
    unsigned short vals[16] = {vr[0].x, vr[0].y, vr[0].z, vr[0].w,
                               vr[1].x, vr[1].y, vr[1].z, vr[1].w,
                               vr[2].x, vr[2].y, vr[2].z, vr[2].w,
                               vr[3].x, vr[3].y, vr[3].z, vr[3].w};
#pragma unroll
    for (int e = 0; e < 16; ++e) {
      int d = vd0 + e;
      *(unsigned short*)(Vt[buf] + ((d * 128 + vn * 2) ^ ((d & 7) << 4))) = vals[e];
    }
  };
  auto KSTAGE = [&](long long nt, int buf) {
#pragma unroll
    for (int p = 0; p < 2; ++p) {
      int id = p * 256 + tid;
      int r = id >> 3, c = id & 7;
      gload16(Kg + (nt + r) * 3072 + ((c ^ (r & 7)) * 8), Kt[buf] + id * 16);
    }
  };

  KSTAGE(n0, 0);
  VLOAD(n0);
  VWRITE(0);
  __syncthreads();

  for (int t = 0; t < 8; ++t) {
    const int cur = t & 1;
    if (t < 7) {
      KSTAGE(n0 + (t + 1) * 64, cur ^ 1);
      VLOAD(n0 + (t + 1) * 64);
    }

    f32x4 accT[4][4];
#pragma unroll
    for (int i = 0; i < 4; ++i)
#pragma unroll
      for (int j = 0; j < 4; ++j) accT[i][j] = (f32x4){0.f, 0.f, 0.f, 0.f};
#pragma unroll
    for (int kc = 0; kc < 2; ++kc) {
      const int koff = (kc * 64 + hi * 16) ^ rswz;
      bf16x8 kv[4], bq[4];
#pragma unroll
      for (int nj = 0; nj < 4; ++nj)
        kv[nj] = *(bf16x8*)(Kt[cur] + (nj * 16 + ln) * 128 + koff);
#pragma unroll
      for (int mi = 0; mi < 4; ++mi)
        bq[mi] = *(const bf16x8*)(pjB + (w * 64 + mi * 16 + ln) * 64 + kc * 32 + hi * 8);
      __builtin_amdgcn_s_setprio(1);
#pragma unroll
      for (int mi = 0; mi < 4; ++mi)
#pragma unroll
        for (int nj = 0; nj < 4; ++nj)
          accT[mi][nj] = __builtin_amdgcn_mfma_f32_16x16x32_bf16(bq[mi], kv[nj], accT[mi][nj], 0, 0, 0);
      __builtin_amdgcn_s_setprio(0);
    }

#pragma unroll
    for (int nj = 0; nj < 4; ++nj) {
      float mx = accT[0][nj][0];
#pragma unroll
      for (int mi = 0; mi < 4; ++mi)
#pragma unroll
        for (int r = 0; r < 4; ++r) mx = fmaxf(mx, accT[mi][nj][r]);
      mx = fmaxf(mx, __shfl_xor(mx, 16, 64));
      mx = fmaxf(mx, __shfl_xor(mx, 32, 64));
      if (hi == 0) rmaxL[w][nj * 16 + ln] = mx;
    }
    {
      int r = tid >> 2, q = tid & 3;
      int b0 = (r * 128 + q * 32) ^ ((r & 7) << 4);
      int b1 = (r * 128 + q * 32 + 16) ^ ((r & 7) << 4);
      u32x4 x0 = *(u32x4*)(Kt[cur] + b0);
      u32x4 x1 = *(u32x4*)(Kt[cur] + b1);
      float s = 0.f;
#pragma unroll
      for (int e = 0; e < 4; ++e) {
        float a0 = bf2f((unsigned short)(x0[e] & 0xffff)), a1 = bf2f((unsigned short)(x0[e] >> 16));
        float a2 = bf2f((unsigned short)(x1[e] & 0xffff)), a3 = bf2f((unsigned short)(x1[e] >> 16));
        s += a0 * a0 + a1 * a1 + a2 * a2 + a3 * a3;
      }
      s += __shfl_xor(s, 1, 64);
      s += __shfl_xor(s, 2, 64);
      if (q == 0) ssqL[r] = s;
    }
    __syncthreads();

    float base[4];
#pragma unroll
    for (int nj = 0; nj < 4; ++nj) {
      int n = nj * 16 + ln;
      base[nj] = 0.0625f * ssqL[n] +
                 fmaxf(fmaxf(rmaxL[0][n], rmaxL[1][n]), fmaxf(rmaxL[2][n], rmaxL[3][n]));
    }
#pragma unroll
    for (int mi = 0; mi < 4; ++mi)
#pragma unroll
      for (int nj = 0; nj < 4; ++nj)
#pragma unroll
        for (int r = 0; r < 4; ++r) {
          float v = 0.0625f * (expf(accT[mi][nj][r] - base[nj]) + 1e-4f);
          int m = w * 64 + mi * 16 + hi * 4 + r;
          int n = nj * 16 + ln;
          *(unsigned short*)(Pt + ((m * 128 + n * 2) ^ ((m & 7) << 4))) = f2b(v);
        }
    if (t < 7) VWRITE(cur ^ 1);
    __syncthreads();

#pragma unroll
    for (int kc = 0; kc < 2; ++kc) {
      const int koff = (kc * 64 + hi * 16) ^ rswz;
      bf16x8 am[4], bv[4];
#pragma unroll
      for (int i = 0; i < 4; ++i)
        am[i] = *(bf16x8*)(Pt + (w * 64 + i * 16 + ln) * 128 + koff);
#pragma unroll
      for (int j = 0; j < 4; ++j)
        bv[j] = *(bf16x8*)(Vt[cur] + (j * 16 + ln) * 128 + koff);
      __builtin_amdgcn_s_setprio(1);
#pragma unroll
      for (int i = 0; i < 4; ++i)
#pragma unroll
        for (int j = 0; j < 4; ++j)
          accC[i][j] = __builtin_amdgcn_mfma_f32_16x16x32_bf16(am[i], bv[j], accC[i][j], 0, 0, 0);
#pragma unroll
      for (int i = 0; i < 4; ++i)
        accK[i] = __builtin_amdgcn_mfma_f32_16x16x32_bf16(am[i], onesf, accK[i], 0, 0, 0);
      __builtin_amdgcn_s_setprio(0);
    }
  }

  if (ln == 0) {
#pragma unroll
    for (int mi = 0; mi < 4; ++mi)
#pragma unroll
      for (int r = 0; r < 4; ++r)
        ksumP[((long long)z * 8 + sp) * 256 + w * 64 + mi * 16 + hi * 4 + r] = accK[mi][r];
  }

  float* ctxPs = ctxP + ((long long)z * 8 + sp) * 16384;
#pragma unroll
  for (int dh = 0; dh < 2; ++dh) {
    __syncthreads();
#pragma unroll
    for (int i = 0; i < 4; ++i)
#pragma unroll
      for (int jj = 0; jj < 2; ++jj) {
        int j = dh * 2 + jj;
#pragma unroll
        for (int r = 0; r < 4; ++r) {
          int m = w * 64 + i * 16 + hi * 4 + r;
          int dl = jj * 16 + ln;
          *(float*)(Pt + ((m * 128 + dl * 4) ^ ((m & 7) << 4))) = accC[i][j][r];
        }
      }
    __syncthreads();
#pragma unroll
    for (int p = 0; p < 8; ++p) {
      int idx = p * 256 + tid;
      int row = idx >> 3, seg = idx & 7;
      u32x4 v = *(u32x4*)(Pt + ((row * 128 + seg * 16) ^ ((row & 7) << 4)));
      __builtin_nontemporal_store(v, (u32x4*)(ctxPs + dh * 8192 + row * 32 + seg * 4));
    }
  }
}

// reduce 8 partials (fixed order) -> swizzled bf16 ctx^T + ksum
__launch_bounds__(256)
__global__ void ctx_fin(const float* __restrict__ ctxP, const float* __restrict__ ksumP,
                        unsigned short* __restrict__ ctxbf, float* __restrict__ ksumF) {
  __shared__ float acc[16384];
  const int z = blockIdx.x;
  const int tid = threadIdx.x;
  const float* base = ctxP + (long long)z * 8 * 16384;
  for (int i = tid; i < 16384; i += 256) {
    float s = 0.f;
#pragma unroll
    for (int q = 0; q < 8; ++q) s += base[(long long)q * 16384 + i];
    acc[i] = s;
  }
  {
    const float* kb = ksumP + (long long)z * 8 * 256;
    float s = 0.f;
#pragma unroll
    for (int q = 0; q < 8; ++q) s += kb[q * 256 + tid];
    ksumF[z * 256 + tid] = s;
  }
  __syncthreads();
  unsigned short* dst = ctxbf + (long long)z * 16384;
  for (int cc = tid; cc < 2048; cc += 256) {
    int mh = cc >> 10, rem = cc & 1023, d = rem >> 4, cl = rem & 15;
    int m0 = mh * 128 + cl * 8;
    int dh = d >> 5, dl = d & 31;
    ushort4 o0, o1;
    o0.x = f2b(acc[dh * 8192 + (m0 + 0) * 32 + dl]);
    o0.y = f2b(acc[dh * 8192 + (m0 + 1) * 32 + dl]);
    o0.z = f2b(acc[dh * 8192 + (m0 + 2) * 32 + dl]);
    o0.w = f2b(acc[dh * 8192 + (m0 + 3) * 32 + dl]);
    o1.x = f2b(acc[dh * 8192 + (m0 + 4) * 32 + dl]);
    o1.y = f2b(acc[dh * 8192 + (m0 + 5) * 32 + dl]);
    o1.z = f2b(acc[dh * 8192 + (m0 + 6) * 32 + dl]);
    o1.w = f2b(acc[dh * 8192 + (m0 + 7) * 32 + dl]);
    unsigned short* p = dst + (long long)mh * 8192 + (d * 16 + (cl ^ (d & 7))) * 8;
    *(ushort4*)p = o0;
    *(ushort4*)(p + 4) = o1;
  }
}

// ---------------------------------------------------------------------------
// Fused Q-feature + denom + PV (r17 verified).
// ---------------------------------------------------------------------------
__launch_bounds__(256)
__global__ void ao_fused(const unsigned short* __restrict__ QKV,
                         const unsigned short* __restrict__ pjB,
                         const float* __restrict__ ksum,
                         const unsigned short* __restrict__ ctxbf,
                         unsigned short* __restrict__ AO) {
  __shared__ char Qt[8192];
  __shared__ char Ps[32768];
  __shared__ char Ch[32768];
  __shared__ float rmaxL[4][64];
  __shared__ float ssqL[64];
  __shared__ float dprt[4][64];
  __shared__ float denomS[64];
  __shared__ float ksL[256];
  const int z = blockIdx.z, b = z >> 4, hh = z & 15;
  const int n0 = blockIdx.x * 64;
  const unsigned short* Qg = QKV + (long long)(b * 4096) * 3072 + hh * 64;
  const int tid = threadIdx.x;
  const int w = tid >> 6, lane = tid & 63;
  const int ln = lane & 15, hi = lane >> 4;
  const int rswz = (ln & 7) << 4;

#pragma unroll
  for (int p = 0; p < 8; ++p) {
    int id = p * 256 + tid;
    gload16(ctxbf + (long long)z * 16384 + id * 8, Ch + id * 16);
  }
#pragma unroll
  for (int p = 0; p < 2; ++p) {
    int id = p * 256 + tid;
    int r = id >> 3, c = id & 7;
    gload16(Qg + (long long)(n0 + r) * 3072 + ((c ^ (r & 7)) * 8), Qt + id * 16);
  }
  ksL[tid] = ksum[z * 256 + tid];
  __syncthreads();

  f32x4 accT[4][4];
#pragma unroll
  for (int i = 0; i < 4; ++i)
#pragma unroll
    for (int j = 0; j < 4; ++j) accT[i][j] = (f32x4){0.f, 0.f, 0.f, 0.f};
#pragma unroll
  for (int kc = 0; kc < 2; ++kc) {
    const int koff = (kc * 64 + hi * 16) ^ rswz;
    bf16x8 qv[4], bq[4];
#pragma unroll
    for (int nj = 0; nj < 4; ++nj)
      qv[nj] = *(bf16x8*)(Qt + (nj * 16 + ln) * 128 + koff);
#pragma unroll
    for (int mi = 0; mi < 4; ++mi)
      bq[mi] = *(const bf16x8*)(pjB + (w * 64 + mi * 16 + ln) * 64 + kc * 32 + hi * 8);
    __builtin_amdgcn_s_setprio(1);
#pragma unroll
    for (int mi = 0; mi < 4; ++mi)
#pragma unroll
      for (int nj = 0; nj < 4; ++nj)
        accT[mi][nj] = __builtin_amdgcn_mfma_f32_16x16x32_bf16(bq[mi], qv[nj], accT[mi][nj], 0, 0, 0);
    __builtin_amdgcn_s_setprio(0);
  }

#pragma unroll
  for (int nj = 0; nj < 4; ++nj) {
    float mx = accT[0][nj][0];
#pragma unroll
    for (int mi = 0; mi < 4; ++mi)
#pragma unroll
      for (int r = 0; r < 4; ++r) mx = fmaxf(mx, accT[mi][nj][r]);
    mx = fmaxf(mx, __shfl_xor(mx, 16, 64));
    mx = fmaxf(mx, __shfl_xor(mx, 32, 64));
    if (hi == 0) rmaxL[w][nj * 16 + ln] = mx;
  }
  {
    int r = tid >> 2, q = tid & 3;
    int b0 = (r * 128 + q * 32) ^ ((r & 7) << 4);
    int b1 = (r * 128 + q * 32 + 16) ^ ((r & 7) << 4);
    u32x4 x0 = *(u32x4*)(Qt + b0);
    u32x4 x1 = *(u32x4*)(Qt + b1);
    float s = 0.f;
#pragma unroll
    for (int e = 0; e < 4; ++e) {
      float a0 = bf2f((unsigned short)(x0[e] & 0xffff)), a1 = bf2f((unsigned short)(x0[e] >> 16));
      float a2 = bf2f((unsigned short)(x1[e] & 0xffff)), a3 = bf2f((unsigned short)(x1[e] >> 16));
      s += a0 * a0 + a1 * a1 + a2 * a2 + a3 * a3;
    }
    s += __shfl_xor(s, 1, 64);
    s += __shfl_xor(s, 2, 64);
    if (q == 0) ssqL[r] = s;
  }
  __syncthreads();

  float base[4];
#pragma unroll
  for (int nj = 0; nj < 4; ++nj) {
    int n = nj * 16 + ln;
    base[nj] = 0.0625f * ssqL[n] +
               fmaxf(fmaxf(rmaxL[0][n], rmaxL[1][n]), fmaxf(rmaxL[2][n], rmaxL[3][n]));
  }
  float ksv[4][4];
#pragma unroll
  for (int mi = 0; mi < 4; ++mi)
#pragma unroll
    for (int r = 0; r < 4; ++r)
      ksv[mi][r] = ksL[w * 64 + mi * 16 + hi * 4 + r];
  float dp[4] = {0.f, 0.f, 0.f, 0.f};
#pragma unroll
  for (int mi = 0; mi < 4; ++mi)
#pragma unroll
    for (int nj = 0; nj < 4; ++nj)
#pragma unroll
      for (int r = 0; r < 4; ++r) {
        float v = 0.0625f * (expf(accT[mi][nj][r] - base[nj]) + 1e-4f);
        unsigned short vb = f2b(v);
        int m = w * 64 + mi * 16 + hi * 4 + r;
        int n = nj * 16 + ln;
        *(unsigned short*)(Ps + n * 512 + ((m * 2) ^ ((n & 7) << 4))) = vb;
        dp[nj] += bf2f(vb) * ksv[mi][r];
      }
#pragma unroll
  for (int nj = 0; nj < 4; ++nj) {
    dp[nj] += __shfl_xor(dp[nj], 16, 64);
    dp[nj] += __shfl_xor(dp[nj], 32, 64);
    if (hi == 0) dprt[w][nj * 16 + ln] = dp[nj];
  }
  __syncthreads();
  if (tid < 64) denomS[tid] = dprt[0][tid] + dprt[1][tid] + dprt[2][tid] + dprt[3][tid];

  f32x4 accO[4];
#pragma unroll
  for (int j = 0; j < 4; ++j) accO[j] = (f32x4){0.f, 0.f, 0.f, 0.f};
#pragma unroll
  for (int mh = 0; mh < 2; ++mh) {
#pragma unroll
    for (int ms = 0; ms < 4; ++ms) {
      const int koff = (ms * 64 + hi * 16);
      bf16x8 ap = *(bf16x8*)(Ps + (w * 16 + ln) * 512 + ((mh * 256 + koff) ^ rswz));
      bf16x8 bc[4];
#pragma unroll
      for (int j = 0; j < 4; ++j)
        bc[j] = *(bf16x8*)(Ch + mh * 16384 + (j * 16 + ln) * 256 + (koff ^ rswz));
      __builtin_amdgcn_s_setprio(1);
#pragma unroll
      for (int j = 0; j < 4; ++j)
        accO[j] = __builtin_amdgcn_mfma_f32_16x16x32_bf16(ap, bc[j], accO[j], 0, 0, 0);
      __builtin_amdgcn_s_setprio(0);
    }
  }
  __syncthreads();

  float inv[4];
#pragma unroll
  for (int r = 0; r < 4; ++r) inv[r] = 1.0f / denomS[w * 16 + hi * 4 + r];
  char* Ct = Qt;
#pragma unroll
  for (int j = 0; j < 4; ++j)
#pragma unroll
    for (int r = 0; r < 4; ++r) {
      int n = w * 16 + hi * 4 + r;
      int d = j * 16 + ln;
      *(unsigned short*)(Ct + ((n * 128 + d * 2) ^ ((n & 7) << 4))) = f2b(accO[j][r] * inv[r]);
    }
  __syncthreads();
#pragma unroll
  for (int p = 0; p < 2; ++p) {
    int idx = p * 256 + tid;
    int row = idx >> 3, seg = idx & 7;
    u32x4 v = *(u32x4*)(Ct + ((row * 128 + seg * 16) ^ ((row & 7) << 4)));
    *(u32x4*)(AO + (long long)(b * 4096 + n0 + row) * 1024 + hh * 64 + seg * 8) = v;
  }
}

// weight transpose+convert: out[n*K+k] = bf16(in[k*N+n])
__launch_bounds__(256)
__global__ void wt_cvt(const float* __restrict__ in, unsigned short* __restrict__ out,
                       int K, int N) {
  __shared__ float t[32][33];
  int k0 = blockIdx.y * 32, n0 = blockIdx.x * 32;
  int tx = threadIdx.x & 31, ty = threadIdx.x >> 5;
  for (int r = ty; r < 32; r += 8) t[r][tx] = in[(long long)(k0 + r) * N + n0 + tx];
  __syncthreads();
  for (int r = ty; r < 32; r += 8) out[(long long)(n0 + r) * K + k0 + tx] = f2b(t[tx][r]);
}

// batched 1024x1024 weight transpose+convert: 4 weights in one launch
__launch_bounds__(256)
__global__ void wt_cvt4(const float* __restrict__ w0, const float* __restrict__ w1,
                        const float* __restrict__ w2, const float* __restrict__ w3,
                        unsigned short* __restrict__ out) {
  __shared__ float t[32][33];
  const float* in = (blockIdx.z == 0) ? w0 : (blockIdx.z == 1) ? w1
                    : (blockIdx.z == 2) ? w2 : w3;
  unsigned short* o = out + (long long)blockIdx.z * 1048576;
  int k0 = blockIdx.y * 32, n0 = blockIdx.x * 32;
  int tx = threadIdx.x & 31, ty = threadIdx.x >> 5;
  for (int r = ty; r < 32; r += 8) t[r][tx] = in[(long long)(k0 + r) * H_ + n0 + tx];
  __syncthreads();
  for (int r = ty; r < 32; r += 8) o[(long long)(n0 + r) * H_ + k0 + tx] = f2b(t[tx][r]);
}

// both projection matrices in one launch
__launch_bounds__(256)
__global__ void projB_cvt2(const float* __restrict__ pj_sa, const float* __restrict__ pj_ca,
                           unsigned short* __restrict__ out) {
  int i = blockIdx.x * 256 + threadIdx.x;
  const float* src = (i < 16384) ? pj_sa : pj_ca;
  out[i] = f2b(0.35355339059327373f * src[i & 16383]);
}

// bias concat
__launch_bounds__(256)
__global__ void bias_cat(const float* __restrict__ b0, const float* __restrict__ b1,
                         const float* __restrict__ b2, float* __restrict__ out) {
  int i = blockIdx.x * 256 + threadIdx.x;
  float v;
  if (i < 1024) v = b0[i];
  else if (i < 2048) v = b1[i - 1024];
  else v = b2[i - 2048];
  out[i] = v;
}

__launch_bounds__(256)
__global__ void cvt_bf16(const float* __restrict__ in, unsigned short* __restrict__ out,
                         long long n) {
  long long stride = (long long)gridDim.x * 1024;
  for (long long i = ((long long)blockIdx.x * 256 + threadIdx.x) * 4; i < n; i += stride) {
    float4 v = *(const float4*)&in[i];
    ushort4 o;
    o.x = f2b(v.x); o.y = f2b(v.y); o.z = f2b(v.z); o.w = f2b(v.w);
    *(ushort4*)&out[i] = o;
  }
}

// out = LN(res + po) * g + beta, rows of 1024.
__launch_bounds__(256)
__global__ void ln_k(const float* __restrict__ resf, const unsigned short* __restrict__ resb,
                     const unsigned short* __restrict__ po,
                     const float* __restrict__ g, const float* __restrict__ be,
                     float* __restrict__ outf, unsigned short* __restrict__ outb) {
  long long row = blockIdx.x;
  int t = threadIdx.x;
  float x0, x1, x2, x3;
  if (resf) {
    float4 va = ((const float4*)(resf + row * H_))[t];
    x0 = va.x; x1 = va.y; x2 = va.z; x3 = va.w;
  } else {
    ushort4 va = ((const ushort4*)(resb + row * H_))[t];
    x0 = bf2f(va.x); x1 = bf2f(va.y); x2 = bf2f(va.z); x3 = bf2f(va.w);
  }
  {
    ushort4 vp = ((const ushort4*)(po + row * H_))[t];
    x0 += bf2f(vp.x); x1 += bf2f(vp.y); x2 += bf2f(vp.z); x3 += bf2f(vp.w);
  }
  float s = x0 + x1 + x2 + x3;
  float q = x0 * x0 + x1 * x1 + x2 * x2 + x3 * x3;
#pragma unroll
  for (int m = 1; m < 64; m <<= 1) { s += __shfl_xor(s, m, 64); q += __shfl_xor(q, m, 64); }
  __shared__ float ssum[4], ssq[4];
  int w = t >> 6, lane = t & 63;
  if (lane == 0) { ssum[w] = s; ssq[w] = q; }
  __syncthreads();
  s = ssum[0] + ssum[1] + ssum[2] + ssum[3];
  q = ssq[0] + ssq[1] + ssq[2] + ssq[3];
  float mean = s * (1.0f / H_);
  float var = q * (1.0f / H_) - mean * mean;
  float rstd = rsqrtf(var + 1e-5f);
  float4 vg = ((const float4*)g)[t];
  float4 vbe = ((const float4*)be)[t];
  float o0 = (x0 - mean) * rstd * vg.x + vbe.x;
  float o1 = (x1 - mean) * rstd * vg.y + vbe.y;
  float o2 = (x2 - mean) * rstd * vg.z + vbe.z;
  float o3 = (x3 - mean) * rstd * vg.w + vbe.w;
  if (outf) {
    float4 o; o.x = o0; o.y = o1; o.z = o2; o.w = o3;
    ((float4*)(outf + row * H_))[t] = o;
  }
  if (outb) {
    ushort4 ob; ob.x = f2b(o0); ob.y = f2b(o1); ob.z = f2b(o2); ob.w = f2b(o3);
    ((ushort4*)(outb + row * H_))[t] = ob;
  }
}

extern "C" void kernel_launch(void* const* d_in, const int* in_sizes, int n_in,
                              void* d_out, int out_size, void* d_ws, size_t ws_size,
                              hipStream_t stream) {
  (void)in_sizes; (void)n_in; (void)out_size; (void)ws_size;
  const float* x      = (const float*)d_in[0];
  const float* enc    = (const float*)d_in[1];
  const float* sa_w[4] = {(const float*)d_in[2], (const float*)d_in[4], (const float*)d_in[6], (const float*)d_in[8]};
  const float* sa_b[4] = {(const float*)d_in[3], (const float*)d_in[5], (const float*)d_in[7], (const float*)d_in[9]};
  const float* sa_pj  = (const float*)d_in[10];
  const float* ca_w[4] = {(const float*)d_in[11], (const float*)d_in[13], (const float*)d_in[15], (const float*)d_in[17]};
  const float* ca_b[4] = {(const float*)d_in[12], (const float*)d_in[14], (const float*)d_in[16], (const float*)d_in[18]};
  const float* ca_pj  = (const float*)d_in[19];
  const float* ff_w1  = (const float*)d_in[20];
  const float* ff_b1  = (const float*)d_in[21];
  const float* ff_w2  = (const float*)d_in[22];
  const float* ff_b2  = (const float*)d_in[23];
  const float* ln1_g  = (const float*)d_in[24];
  const float* ln1_b  = (const float*)d_in[25];
  const float* ln2_g  = (const float*)d_in[26];
  const float* ln2_b  = (const float*)d_in[27];
  const float* ln3_g  = (const float*)d_in[28];
  const float* ln3_b  = (const float*)d_in[29];

  float* ws = (float*)d_ws;
  unsigned short* XB = (unsigned short*)(ws);                 // [16384][1024] bf16
  unsigned short* EB = (unsigned short*)(ws + 8388608LL);     // enc bf16 / AO / ffT
  unsigned short* QKVb = (unsigned short*)(ws + 16777216LL);  // [16384][3072] bf16
  unsigned short* PO = (unsigned short*)(ws + 41943040LL);    // [16384][1024] bf16
  float* ctxP = ws + 41943040LL;                               // ALIAS of PO
  unsigned short* MID2 = QKVb;                                 // FFN mid chunk [8192][4096]
  unsigned short* FO2 = PO;                                    // FFN out chunk [8192][1024]
  unsigned short* WTph = (unsigned short*)(ws + 52428800LL);  // 4 x [1024][1024] bf16
  unsigned short* pjB = (unsigned short*)(ws + 54525952LL);   // 2 x [256][64] bf16
  float* ksumP = ws + 54542336LL;                              // [64][8][256] f32
  float* ksumF = ws + 54673408LL;                              // [64][256] f32
  unsigned short* ctxbf = (unsigned short*)(ws + 55607296LL); // [64][16384] bf16
  float* biasC = ws + 56131584LL;                              // [3072] f32

  unsigned short* ff1T = EB;
  unsigned short* ff2T = EB + 4194304LL;
  unsigned short* pjB_sa = pjB, *pjB_ca = pjB + 16384;

  dim3 blk(256, 1, 1);
  dim3 blk512(512, 1, 1);
  const int LDQ = 3072;

  projB_cvt2<<<dim3(128), blk, 0, stream>>>(sa_pj, ca_pj, pjB);
  cvt_bf16<<<dim3(2048), blk, 0, stream>>>(x, XB, 16777216LL);

  auto attn_core = [&](const unsigned short* pj, const float* wo_bias) {
    ctxksum_mfma<<<dim3(8, 1, 64), blk, 0, stream>>>(QKVb, pj, ksumP, ctxP);
    ctx_fin<<<dim3(64), blk, 0, stream>>>(ctxP, ksumP, ctxbf, ksumF);
    ao_fused<<<dim3(64, 1, 64), blk, 0, stream>>>(QKVb, pj, ksumF, ctxbf, EB);
    gemm256<0><<<dim3(4, 64), blk512, 0, stream>>>(EB, H_, WTph + 3145728, wo_bias, PO, H_, H_);
  };

  // ---- self-attention ----
  wt_cvt4<<<dim3(32, 32, 4), blk, 0, stream>>>(sa_w[0], sa_w[1], sa_w[2], sa_w[3], WTph);
  bias_cat<<<dim3(12), blk, 0, stream>>>(sa_b[0], sa_b[1], sa_b[2], biasC);
  gemm256<0><<<dim3(12, 64), blk512, 0, stream>>>(XB, H_, WTph, biasC, QKVb, LDQ, H_);
  attn_core(pjB_sa, sa_b[3]);
  ln_k<<<dim3(16384), blk, 0, stream>>>(x, nullptr, PO, ln1_g, ln1_b, nullptr, XB);

  // ---- cross-attention ----
  cvt_bf16<<<dim3(2048), blk, 0, stream>>>(enc, EB, 16777216LL);
  wt_cvt4<<<dim3(32, 32, 4), blk, 0, stream>>>(ca_w[0], ca_w[1], ca_w[2], ca_w[3], WTph);
  bias_cat<<<dim3(8), blk, 0, stream>>>(ca_b[1], ca_b[2], nullptr, biasC);
  gemm256<0><<<dim3(4, 64), blk512, 0, stream>>>(XB, H_, WTph, ca_b[0], QKVb, LDQ, H_);
  gemm256<0><<<dim3(8, 64), blk512, 0, stream>>>(EB, H_, WTph + 1048576, biasC, QKVb + 1024, LDQ, H_);
  attn_core(pjB_ca, ca_b[3]);
  ln_k<<<dim3(16384), blk, 0, stream>>>(nullptr, XB, PO, ln2_g, ln2_b, nullptr, XB);

  // ---- FFN: 2 chunks of 8192 rows ----
  wt_cvt<<<dim3(128, 32), blk, 0, stream>>>(ff_w1, ff1T, H_, 4096);
  wt_cvt<<<dim3(32, 128), blk, 0, stream>>>(ff_w2, ff2T, 4096, H_);
  for (int c = 0; c < 2; ++c) {
    const long long co = (long long)c * 8192 * H_;
    gemm256<1><<<dim3(16, 32), blk512, 0, stream>>>(XB + co, H_, ff1T, ff_b1, MID2, 4096, H_);
    gemm256<0><<<dim3(4, 32), blk512, 0, stream>>>(MID2, 4096, ff2T, ff_b2, FO2, H_, 4096);
    ln_k<<<dim3(8192), blk, 0, stream>>>(nullptr, XB + co, FO2, ln3_g, ln3_b,
                                         (float*)d_out + co, nullptr);
  }
}

// Round 21
// 1240.580 us; speedup vs baseline: 1.0213x; 1.0213x over previous
//
#include <hip/hip_runtime.h>
#include <hip/hip_bf16.h>

#define B_ 4
#define N_ 4096
#define H_ 1024
#define NH_ 16
#define HD_ 64
#define M_ 256

typedef __attribute__((ext_vector_type(8))) __bf16 bf16x8;
typedef __attribute__((ext_vector_type(4))) float f32x4;
typedef __attribute__((ext_vector_type(4))) unsigned int u32x4;

__device__ __forceinline__ float bf2f(unsigned short u) {
  union { unsigned int i; float f; } x; x.i = ((unsigned int)u) << 16; return x.f;
}
__device__ __forceinline__ unsigned short f2b(float f) {
  __hip_bfloat16 h = __float2bfloat16(f);
  return *(unsigned short*)&h;
}
__device__ __forceinline__ float gelu_f(float x) {
  const float c = 0.7978845608028654f;
  float t = tanhf(c * (x + 0.044715f * x * x * x));
  return 0.5f * x * (1.0f + t);
}
__device__ __forceinline__ bf16x8 ones8() {
  union { unsigned int u[4]; bf16x8 v; } o;
  o.u[0] = 0x3F803F80u; o.u[1] = 0x3F803F80u; o.u[2] = 0x3F803F80u; o.u[3] = 0x3F803F80u;
  return o.v;
}

typedef __attribute__((address_space(3))) unsigned int as3_uint;
typedef const __attribute__((address_space(1))) unsigned int as1_uint;
__device__ __forceinline__ void gload16(const void* g, void* l) {
  __builtin_amdgcn_global_load_lds((as1_uint*)g, (as3_uint*)l, 16, 0, 0);
}

// ---------------------------------------------------------------------------
// Dense bf16 MFMA GEMM with CORRECTED T4 counted-vmcnt pipelining (r19
// verified). Per K-step: STAGE(t+1); vmcnt(8); publish s_barrier;
// COMPUTE(t); free s_barrier.
// ---------------------------------------------------------------------------
template<int ACT>
__launch_bounds__(256)
__global__ void gemm_mfma(const unsigned short* __restrict__ A, int lda,
                          const unsigned short* __restrict__ BT,
                          const float* __restrict__ bias,
                          unsigned short* __restrict__ C, int ldc, int K) {
  __shared__ __align__(16) char LDS[65536];

  const int tid = threadIdx.x;
  const int nwg = gridDim.x * gridDim.y;
  const int lin = blockIdx.y * gridDim.x + blockIdx.x;
  const int mm = (lin & 7) * (nwg >> 3) + (lin >> 3);
  const int bx = mm % gridDim.x, by = mm / gridDim.x;
  const int row0 = by * 128;
  const int col0 = bx * 128;

  const int w = tid >> 6, lane = tid & 63;
  const int wm = w >> 1, wn = w & 1;
  const int ln = lane & 15, hi = lane >> 4;
  const int rswz = (ln & 7) << 4;

  const int srow = w * 8 + (lane >> 3);
  const int schunk = ((lane & 7) ^ (lane >> 3)) * 8;
  const unsigned short* Ag = A + (long long)(row0 + srow) * lda + schunk;
  const unsigned short* Bg = BT + (long long)(col0 + srow) * K + schunk;
  const int ldsw = w * 1024;

  f32x4 acc[4][4];
#pragma unroll
  for (int i = 0; i < 4; ++i)
#pragma unroll
    for (int j = 0; j < 4; ++j) acc[i][j] = (f32x4){0.f, 0.f, 0.f, 0.f};

  auto STAGE = [&](int p, int k0) {
    char* dst = LDS + p * 32768 + ldsw;
#pragma unroll
    for (int i = 0; i < 4; ++i) {
      gload16(Ag + (long long)i * 32 * lda + k0, dst + i * 4096);
      gload16(Bg + (long long)i * 32 * K + k0, dst + 16384 + i * 4096);
    }
  };
  auto COMPUTE = [&](int p) {
    char* AsB = LDS + p * 32768;
    char* BsB = AsB + 16384;
#pragma unroll
    for (int kc = 0; kc < 2; ++kc) {
      const int koff = (kc * 64 + hi * 16) ^ rswz;
      bf16x8 av[4], bv[4];
#pragma unroll
      for (int i = 0; i < 4; ++i)
        av[i] = *(bf16x8*)(AsB + (wm * 64 + i * 16 + ln) * 128 + koff);
#pragma unroll
      for (int j = 0; j < 4; ++j)
        bv[j] = *(bf16x8*)(BsB + (wn * 64 + j * 16 + ln) * 128 + koff);
      __builtin_amdgcn_s_setprio(1);
#pragma unroll
      for (int i = 0; i < 4; ++i)
#pragma unroll
        for (int j = 0; j < 4; ++j)
          acc[i][j] = __builtin_amdgcn_mfma_f32_16x16x32_bf16(av[i], bv[j], acc[i][j], 0, 0, 0);
      __builtin_amdgcn_s_setprio(0);
    }
  };

  const int nT = K >> 6;
  STAGE(0, 0);
  int cur = 0;
  for (int t = 0; t < nT; ++t) {
    if (t + 1 < nT) {
      STAGE(cur ^ 1, (t + 1) * 64);
      asm volatile("s_waitcnt vmcnt(8)" ::: "memory");   // own tile-t loads done
    } else {
      asm volatile("s_waitcnt vmcnt(0)" ::: "memory");
    }
    __builtin_amdgcn_sched_barrier(0);
    __builtin_amdgcn_s_barrier();   // publish tile t across waves
    COMPUTE(cur);
    __builtin_amdgcn_s_barrier();   // buffer cur free before next STAGE hits it
    cur ^= 1;
  }

  char* SB = LDS;
#pragma unroll
  for (int j = 0; j < 4; ++j) {
    const int lcol = wn * 64 + j * 16 + ln;
    const float bj = bias ? bias[col0 + lcol] : 0.0f;
#pragma unroll
    for (int i = 0; i < 4; ++i) {
      const int rb_ = wm * 64 + i * 16 + hi * 4;
#pragma unroll
      for (int r = 0; r < 4; ++r) {
        float v = acc[i][j][r] + bj;
        if (ACT == 1) v = gelu_f(v);
        const int row = rb_ + r;
        *(unsigned short*)(SB + ((row * 256 + lcol * 2) ^ ((row & 7) << 4))) = f2b(v);
      }
    }
  }
  __syncthreads();
#pragma unroll
  for (int p = 0; p < 8; ++p) {
    const int idx = p * 256 + tid;
    const int row = idx >> 4, seg = idx & 15;
    u32x4 v = *(u32x4*)(SB + ((row * 256 + seg * 16) ^ ((row & 7) << 4)));
    __builtin_nontemporal_store(v, (u32x4*)(C + (long long)(row0 + row) * ldc + col0 + seg * 8));
  }
}

// ---------------------------------------------------------------------------
// Fused K-feature + ctx + ksum (r17 verified: swapped feat MFMA, dbuf K/V
// prefetch, ones-MFMA ksum, no atomics).
// ---------------------------------------------------------------------------
__launch_bounds__(256)
__global__ void ctxksum_mfma(const unsigned short* __restrict__ QKV,
                             const unsigned short* __restrict__ pjB,
                             float* __restrict__ ksumP,     // [64z][8s][256]
                             float* __restrict__ ctxP) {    // [64z*8s][16384]
  __shared__ char Kt[2][8192];
  __shared__ char Vt[2][8192];
  __shared__ char Pt[32768];
  __shared__ float rmaxL[4][64];
  __shared__ float ssqL[64];
  const int z = blockIdx.z, b = z >> 4, hh = z & 15;
  const int sp = blockIdx.x;
  const long long n0 = sp * 512;
  const unsigned short* Kg = QKV + (long long)(b * 4096) * 3072 + 1024 + hh * 64;
  const unsigned short* Vg = QKV + (long long)(b * 4096) * 3072 + 2048 + hh * 64;
  const int tid = threadIdx.x;
  const int w = tid >> 6, lane = tid & 63;
  const int ln = lane & 15, hi = lane >> 4;
  const int rswz = (ln & 7) << 4;
  const bf16x8 onesf = ones8();

  f32x4 accC[4][4];
#pragma unroll
  for (int i = 0; i < 4; ++i)
#pragma unroll
    for (int j = 0; j < 4; ++j) accC[i][j] = (f32x4){0.f, 0.f, 0.f, 0.f};
  f32x4 accK[4];
#pragma unroll
  for (int i = 0; i < 4; ++i) accK[i] = (f32x4){0.f, 0.f, 0.f, 0.f};

  const int vn = tid >> 2, vd0 = (tid & 3) * 16;
  ushort4 vr[4];
  auto VLOAD = [&](long long nt) {
    const unsigned short* src = Vg + (nt + vn) * 3072 + vd0;
    vr[0] = *(const ushort4*)src;
    vr[1] = *(const ushort4*)(src + 4);
    vr[2] = *(const ushort4*)(src + 8);
    vr[3] = *(const ushort4*)(src + 12);
  };
  auto VWRITE = [&](int buf) {
    unsigned short vals[16] = {vr[0].x, vr[0].y, vr[0].z, vr[0].w,
                               vr[1].x, vr[1].y, vr[1].z, vr[1].w,
                               vr[2].x, vr[2].y, vr[2].z, vr[2].w,
                               vr[3].x, vr[3].y, vr[3].z, vr[3].w};
#pragma unroll
    for (int e = 0; e < 16; ++e) {
      int d = vd0 + e;
      *(unsigned short*)(Vt[buf] + ((d * 128 + vn * 2) ^ ((d & 7) << 4))) = vals[e];
    }
  };
  auto KSTAGE = [&](long long nt, int buf) {
#pragma unroll
    for (int p = 0; p < 2; ++p) {
      int id = p * 256 + tid;
      int r = id >> 3, c = id & 7;
      gload16(Kg + (nt + r) * 3072 + ((c ^ (r & 7)) * 8), Kt[buf] + id * 16);
    }
  };

  KSTAGE(n0, 0);
  VLOAD(n0);
  VWRITE(0);
  __syncthreads();

  for (int t = 0; t < 8; ++t) {
    const int cur = t & 1;
    if (t < 7) {
      KSTAGE(n0 + (t + 1) * 64, cur ^ 1);
      VLOAD(n0 + (t + 1) * 64);
    }

    f32x4 accT[4][4];
#pragma unroll
    for (int i = 0; i < 4; ++i)
#pragma unroll
      for (int j = 0; j < 4; ++j) accT[i][j] = (f32x4){0.f, 0.f, 0.f, 0.f};
#pragma unroll
    for (int kc = 0; kc < 2; ++kc) {
      const int koff = (kc * 64 + hi * 16) ^ rswz;
      bf16x8 kv[4], bq[4];
#pragma unroll
      for (int nj = 0; nj < 4; ++nj)
        kv[nj] = *(bf16x8*)(Kt[cur] + (nj * 16 + ln) * 128 + koff);
#pragma unroll
      for (int mi = 0; mi < 4; ++mi)
        bq[mi] = *(const bf16x8*)(pjB + (w * 64 + mi * 16 + ln) * 64 + kc * 32 + hi * 8);
      __builtin_amdgcn_s_setprio(1);
#pragma unroll
      for (int mi = 0; mi < 4; ++mi)
#pragma unroll
        for (int nj = 0; nj < 4; ++nj)
          accT[mi][nj] = __builtin_amdgcn_mfma_f32_16x16x32_bf16(bq[mi], kv[nj], accT[mi][nj], 0, 0, 0);
      __builtin_amdgcn_s_setprio(0);
    }

#pragma unroll
    for (int nj = 0; nj < 4; ++nj) {
      float mx = accT[0][nj][0];
#pragma unroll
      for (int mi = 0; mi < 4; ++mi)
#pragma unroll
        for (int r = 0; r < 4; ++r) mx = fmaxf(mx, accT[mi][nj][r]);
      mx = fmaxf(mx, __shfl_xor(mx, 16, 64));
      mx = fmaxf(mx, __shfl_xor(mx, 32, 64));
      if (hi == 0) rmaxL[w][nj * 16 + ln] = mx;
    }
    {
      int r = tid >> 2, q = tid & 3;
      int b0 = (r * 128 + q * 32) ^ ((r & 7) << 4);
      int b1 = (r * 128 + q * 32 + 16) ^ ((r & 7) << 4);
      u32x4 x0 = *(u32x4*)(Kt[cur] + b0);
      u32x4 x1 = *(u32x4*)(Kt[cur] + b1);
      float s = 0.f;
#pragma unroll
      for (int e = 0; e < 4; ++e) {
        float a0 = bf2f((unsigned short)(x0[e] & 0xffff)), a1 = bf2f((unsigned short)(x0[e] >> 16));
        float a2 = bf2f((unsigned short)(x1[e] & 0xffff)), a3 = bf2f((unsigned short)(x1[e] >> 16));
        s += a0 * a0 + a1 * a1 + a2 * a2 + a3 * a3;
      }
      s += __shfl_xor(s, 1, 64);
      s += __shfl_xor(s, 2, 64);
      if (q == 0) ssqL[r] = s;
    }
    __syncthreads();

    float base[4];
#pragma unroll
    for (int nj = 0; nj < 4; ++nj) {
      int n = nj * 16 + ln;
      base[nj] = 0.0625f * ssqL[n] +
                 fmaxf(fmaxf(rmaxL[0][n], rmaxL[1][n]), fmaxf(rmaxL[2][n], rmaxL[3][n]));
    }
#pragma unroll
    for (int mi = 0; mi < 4; ++mi)
#pragma unroll
      for (int nj = 0; nj < 4; ++nj)
#pragma unroll
        for (int r = 0; r < 4; ++r) {
          float v = 0.0625f * (expf(accT[mi][nj][r] - base[nj]) + 1e-4f);
          int m = w * 64 + mi * 16 + hi * 4 + r;
          int n = nj * 16 + ln;
          *(unsigned short*)(Pt + ((m * 128 + n * 2) ^ ((m & 7) << 4))) = f2b(v);
        }
    if (t < 7) VWRITE(cur ^ 1);
    __syncthreads();

#pragma unroll
    for (int kc = 0; kc < 2; ++kc) {
      const int koff = (kc * 64 + hi * 16) ^ rswz;
      bf16x8 am[4], bv[4];
#pragma unroll
      for (int i = 0; i < 4; ++i)
        am[i] = *(bf16x8*)(Pt + (w * 64 + i * 16 + ln) * 128 + koff);
#pragma unroll
      for (int j = 0; j < 4; ++j)
        bv[j] = *(bf16x8*)(Vt[cur] + (j * 16 + ln) * 128 + koff);
      __builtin_amdgcn_s_setprio(1);
#pragma unroll
      for (int i = 0; i < 4; ++i)
#pragma unroll
        for (int j = 0; j < 4; ++j)
          accC[i][j] = __builtin_amdgcn_mfma_f32_16x16x32_bf16(am[i], bv[j], accC[i][j], 0, 0, 0);
#pragma unroll
      for (int i = 0; i < 4; ++i)
        accK[i] = __builtin_amdgcn_mfma_f32_16x16x32_bf16(am[i], onesf, accK[i], 0, 0, 0);
      __builtin_amdgcn_s_setprio(0);
    }
  }

  if (ln == 0) {
#pragma unroll
    for (int mi = 0; mi < 4; ++mi)
#pragma unroll
      for (int r = 0; r < 4; ++r)
        ksumP[((long long)z * 8 + sp) * 256 + w * 64 + mi * 16 + hi * 4 + r] = accK[mi][r];
  }

  float* ctxPs = ctxP + ((long long)z * 8 + sp) * 16384;
#pragma unroll
  for (int dh = 0; dh < 2; ++dh) {
    __syncthreads();
#pragma unroll
    for (int i = 0; i < 4; ++i)
#pragma unroll
      for (int jj = 0; jj < 2; ++jj) {
        int j = dh * 2 + jj;
#pragma unroll
        for (int r = 0; r < 4; ++r) {
          int m = w * 64 + i * 16 + hi * 4 + r;
          int dl = jj * 16 + ln;
          *(float*)(Pt + ((m * 128 + dl * 4) ^ ((m & 7) << 4))) = accC[i][j][r];
        }
      }
    __syncthreads();
#pragma unroll
    for (int p = 0; p < 8; ++p) {
      int idx = p * 256 + tid;
      int row = idx >> 3, seg = idx & 7;
      u32x4 v = *(u32x4*)(Pt + ((row * 128 + seg * 16) ^ ((row & 7) << 4)));
      __builtin_nontemporal_store(v, (u32x4*)(ctxPs + dh * 8192 + row * 32 + seg * 4));
    }
  }
}

// reduce 8 partials (fixed order) -> swizzled bf16 ctx^T + ksum
__launch_bounds__(256)
__global__ void ctx_fin(const float* __restrict__ ctxP, const float* __restrict__ ksumP,
                        unsigned short* __restrict__ ctxbf, float* __restrict__ ksumF) {
  __shared__ float acc[16384];
  const int z = blockIdx.x;
  const int tid = threadIdx.x;
  const float* base = ctxP + (long long)z * 8 * 16384;
  for (int i = tid; i < 16384; i += 256) {
    float s = 0.f;
#pragma unroll
    for (int q = 0; q < 8; ++q) s += base[(long long)q * 16384 + i];
    acc[i] = s;
  }
  {
    const float* kb = ksumP + (long long)z * 8 * 256;
    float s = 0.f;
#pragma unroll
    for (int q = 0; q < 8; ++q) s += kb[q * 256 + tid];
    ksumF[z * 256 + tid] = s;
  }
  __syncthreads();
  unsigned short* dst = ctxbf + (long long)z * 16384;
  for (int cc = tid; cc < 2048; cc += 256) {
    int mh = cc >> 10, rem = cc & 1023, d = rem >> 4, cl = rem & 15;
    int m0 = mh * 128 + cl * 8;
    int dh = d >> 5, dl = d & 31;
    ushort4 o0, o1;
    o0.x = f2b(acc[dh * 8192 + (m0 + 0) * 32 + dl]);
    o0.y = f2b(acc[dh * 8192 + (m0 + 1) * 32 + dl]);
    o0.z = f2b(acc[dh * 8192 + (m0 + 2) * 32 + dl]);
    o0.w = f2b(acc[dh * 8192 + (m0 + 3) * 32 + dl]);
    o1.x = f2b(acc[dh * 8192 + (m0 + 4) * 32 + dl]);
    o1.y = f2b(acc[dh * 8192 + (m0 + 5) * 32 + dl]);
    o1.z = f2b(acc[dh * 8192 + (m0 + 6) * 32 + dl]);
    o1.w = f2b(acc[dh * 8192 + (m0 + 7) * 32 + dl]);
    unsigned short* p = dst + (long long)mh * 8192 + (d * 16 + (cl ^ (d & 7))) * 8;
    *(ushort4*)p = o0;
    *(ushort4*)(p + 4) = o1;
  }
}

// ---------------------------------------------------------------------------
// Fused Q-feature + denom + PV (r17 verified).
// ---------------------------------------------------------------------------
__launch_bounds__(256)
__global__ void ao_fused(const unsigned short* __restrict__ QKV,
                         const unsigned short* __restrict__ pjB,
                         const float* __restrict__ ksum,
                         const unsigned short* __restrict__ ctxbf,
                         unsigned short* __restrict__ AO) {
  __shared__ char Qt[8192];
  __shared__ char Ps[32768];
  __shared__ char Ch[32768];
  __shared__ float rmaxL[4][64];
  __shared__ float ssqL[64];
  __shared__ float dprt[4][64];
  __shared__ float denomS[64];
  __shared__ float ksL[256];
  const int z = blockIdx.z, b = z >> 4, hh = z & 15;
  const int n0 = blockIdx.x * 64;
  const unsigned short* Qg = QKV + (long long)(b * 4096) * 3072 + hh * 64;
  const int tid = threadIdx.x;
  const int w = tid >> 6, lane = tid & 63;
  const int ln = lane & 15, hi = lane >> 4;
  const int rswz = (ln & 7) << 4;

#pragma unroll
  for (int p = 0; p < 8; ++p) {
    int id = p * 256 + tid;
    gload16(ctxbf + (long long)z * 16384 + id * 8, Ch + id * 16);
  }
#pragma unroll
  for (int p = 0; p < 2; ++p) {
    int id = p * 256 + tid;
    int r = id >> 3, c = id & 7;
    gload16(Qg + (long long)(n0 + r) * 3072 + ((c ^ (r & 7)) * 8), Qt + id * 16);
  }
  ksL[tid] = ksum[z * 256 + tid];
  __syncthreads();

  f32x4 accT[4][4];
#pragma unroll
  for (int i = 0; i < 4; ++i)
#pragma unroll
    for (int j = 0; j < 4; ++j) accT[i][j] = (f32x4){0.f, 0.f, 0.f, 0.f};
#pragma unroll
  for (int kc = 0; kc < 2; ++kc) {
    const int koff = (kc * 64 + hi * 16) ^ rswz;
    bf16x8 qv[4], bq[4];
#pragma unroll
    for (int nj = 0; nj < 4; ++nj)
      qv[nj] = *(bf16x8*)(Qt + (nj * 16 + ln) * 128 + koff);
#pragma unroll
    for (int mi = 0; mi < 4; ++mi)
      bq[mi] = *(const bf16x8*)(pjB + (w * 64 + mi * 16 + ln) * 64 + kc * 32 + hi * 8);
    __builtin_amdgcn_s_setprio(1);
#pragma unroll
    for (int mi = 0; mi < 4; ++mi)
#pragma unroll
      for (int nj = 0; nj < 4; ++nj)
        accT[mi][nj] = __builtin_amdgcn_mfma_f32_16x16x32_bf16(bq[mi], qv[nj], accT[mi][nj], 0, 0, 0);
    __builtin_amdgcn_s_setprio(0);
  }

#pragma unroll
  for (int nj = 0; nj < 4; ++nj) {
    float mx = accT[0][nj][0];
#pragma unroll
    for (int mi = 0; mi < 4; ++mi)
#pragma unroll
      for (int r = 0; r < 4; ++r) mx = fmaxf(mx, accT[mi][nj][r]);
    mx = fmaxf(mx, __shfl_xor(mx, 16, 64));
    mx = fmaxf(mx, __shfl_xor(mx, 32, 64));
    if (hi == 0) rmaxL[w][nj * 16 + ln] = mx;
  }
  {
    int r = tid >> 2, q = tid & 3;
    int b0 = (r * 128 + q * 32) ^ ((r & 7) << 4);
    int b1 = (r * 128 + q * 32 + 16) ^ ((r & 7) << 4);
    u32x4 x0 = *(u32x4*)(Qt + b0);
    u32x4 x1 = *(u32x4*)(Qt + b1);
    float s = 0.f;
#pragma unroll
    for (int e = 0; e < 4; ++e) {
      float a0 = bf2f((unsigned short)(x0[e] & 0xffff)), a1 = bf2f((unsigned short)(x0[e] >> 16));
      float a2 = bf2f((unsigned short)(x1[e] & 0xffff)), a3 = bf2f((unsigned short)(x1[e] >> 16));
      s += a0 * a0 + a1 * a1 + a2 * a2 + a3 * a3;
    }
    s += __shfl_xor(s, 1, 64);
    s += __shfl_xor(s, 2, 64);
    if (q == 0) ssqL[r] = s;
  }
  __syncthreads();

  float base[4];
#pragma unroll
  for (int nj = 0; nj < 4; ++nj) {
    int n = nj * 16 + ln;
    base[nj] = 0.0625f * ssqL[n] +
               fmaxf(fmaxf(rmaxL[0][n], rmaxL[1][n]), fmaxf(rmaxL[2][n], rmaxL[3][n]));
  }
  float ksv[4][4];
#pragma unroll
  for (int mi = 0; mi < 4; ++mi)
#pragma unroll
    for (int r = 0; r < 4; ++r)
      ksv[mi][r] = ksL[w * 64 + mi * 16 + hi * 4 + r];
  float dp[4] = {0.f, 0.f, 0.f, 0.f};
#pragma unroll
  for (int mi = 0; mi < 4; ++mi)
#pragma unroll
    for (int nj = 0; nj < 4; ++nj)
#pragma unroll
      for (int r = 0; r < 4; ++r) {
        float v = 0.0625f * (expf(accT[mi][nj][r] - base[nj]) + 1e-4f);
        unsigned short vb = f2b(v);
        int m = w * 64 + mi * 16 + hi * 4 + r;
        int n = nj * 16 + ln;
        *(unsigned short*)(Ps + n * 512 + ((m * 2) ^ ((n & 7) << 4))) = vb;
        dp[nj] += bf2f(vb) * ksv[mi][r];
      }
#pragma unroll
  for (int nj = 0; nj < 4; ++nj) {
    dp[nj] += __shfl_xor(dp[nj], 16, 64);
    dp[nj] += __shfl_xor(dp[nj], 32, 64);
    if (hi == 0) dprt[w][nj * 16 + ln] = dp[nj];
  }
  __syncthreads();
  if (tid < 64) denomS[tid] = dprt[0][tid] + dprt[1][tid] + dprt[2][tid] + dprt[3][tid];

  f32x4 accO[4];
#pragma unroll
  for (int j = 0; j < 4; ++j) accO[j] = (f32x4){0.f, 0.f, 0.f, 0.f};
#pragma unroll
  for (int mh = 0; mh < 2; ++mh) {
#pragma unroll
    for (int ms = 0; ms < 4; ++ms) {
      const int koff = (ms * 64 + hi * 16);
      bf16x8 ap = *(bf16x8*)(Ps + (w * 16 + ln) * 512 + ((mh * 256 + koff) ^ rswz));
      bf16x8 bc[4];
#pragma unroll
      for (int j = 0; j < 4; ++j)
        bc[j] = *(bf16x8*)(Ch + mh * 16384 + (j * 16 + ln) * 256 + (koff ^ rswz));
      __builtin_amdgcn_s_setprio(1);
#pragma unroll
      for (int j = 0; j < 4; ++j)
        accO[j] = __builtin_amdgcn_mfma_f32_16x16x32_bf16(ap, bc[j], accO[j], 0, 0, 0);
      __builtin_amdgcn_s_setprio(0);
    }
  }
  __syncthreads();

  float inv[4];
#pragma unroll
  for (int r = 0; r < 4; ++r) inv[r] = 1.0f / denomS[w * 16 + hi * 4 + r];
  char* Ct = Qt;
#pragma unroll
  for (int j = 0; j < 4; ++j)
#pragma unroll
    for (int r = 0; r < 4; ++r) {
      int n = w * 16 + hi * 4 + r;
      int d = j * 16 + ln;
      *(unsigned short*)(Ct + ((n * 128 + d * 2) ^ ((n & 7) << 4))) = f2b(accO[j][r] * inv[r]);
    }
  __syncthreads();
#pragma unroll
  for (int p = 0; p < 2; ++p) {
    int idx = p * 256 + tid;
    int row = idx >> 3, seg = idx & 7;
    u32x4 v = *(u32x4*)(Ct + ((row * 128 + seg * 16) ^ ((row & 7) << 4)));
    *(u32x4*)(AO + (long long)(b * 4096 + n0 + row) * 1024 + hh * 64 + seg * 8) = v;
  }
}

// weight transpose+convert: out[n*K+k] = bf16(in[k*N+n])
__launch_bounds__(256)
__global__ void wt_cvt(const float* __restrict__ in, unsigned short* __restrict__ out,
                       int K, int N) {
  __shared__ float t[32][33];
  int k0 = blockIdx.y * 32, n0 = blockIdx.x * 32;
  int tx = threadIdx.x & 31, ty = threadIdx.x >> 5;
  for (int r = ty; r < 32; r += 8) t[r][tx] = in[(long long)(k0 + r) * N + n0 + tx];
  __syncthreads();
  for (int r = ty; r < 32; r += 8) out[(long long)(n0 + r) * K + k0 + tx] = f2b(t[tx][r]);
}

// batched 1024x1024 weight transpose+convert: 4 weights in one launch
__launch_bounds__(256)
__global__ void wt_cvt4(const float* __restrict__ w0, const float* __restrict__ w1,
                        const float* __restrict__ w2, const float* __restrict__ w3,
                        unsigned short* __restrict__ out) {
  __shared__ float t[32][33];
  const float* in = (blockIdx.z == 0) ? w0 : (blockIdx.z == 1) ? w1
                    : (blockIdx.z == 2) ? w2 : w3;
  unsigned short* o = out + (long long)blockIdx.z * 1048576;
  int k0 = blockIdx.y * 32, n0 = blockIdx.x * 32;
  int tx = threadIdx.x & 31, ty = threadIdx.x >> 5;
  for (int r = ty; r < 32; r += 8) t[r][tx] = in[(long long)(k0 + r) * H_ + n0 + tx];
  __syncthreads();
  for (int r = ty; r < 32; r += 8) o[(long long)(n0 + r) * H_ + k0 + tx] = f2b(t[tx][r]);
}

// both projection matrices in one launch
__launch_bounds__(256)
__global__ void projB_cvt2(const float* __restrict__ pj_sa, const float* __restrict__ pj_ca,
                           unsigned short* __restrict__ out) {
  int i = blockIdx.x * 256 + threadIdx.x;
  const float* src = (i < 16384) ? pj_sa : pj_ca;
  out[i] = f2b(0.35355339059327373f * src[i & 16383]);
}

// bias concat
__launch_bounds__(256)
__global__ void bias_cat(const float* __restrict__ b0, const float* __restrict__ b1,
                         const float* __restrict__ b2, float* __restrict__ out) {
  int i = blockIdx.x * 256 + threadIdx.x;
  float v;
  if (i < 1024) v = b0[i];
  else if (i < 2048) v = b1[i - 1024];
  else v = b2[i - 2048];
  out[i] = v;
}

__launch_bounds__(256)
__global__ void cvt_bf16(const float* __restrict__ in, unsigned short* __restrict__ out,
                         long long n) {
  long long stride = (long long)gridDim.x * 1024;
  for (long long i = ((long long)blockIdx.x * 256 + threadIdx.x) * 4; i < n; i += stride) {
    float4 v = *(const float4*)&in[i];
    ushort4 o;
    o.x = f2b(v.x); o.y = f2b(v.y); o.z = f2b(v.z); o.w = f2b(v.w);
    *(ushort4*)&out[i] = o;
  }
}

// out = LN(res + po) * g + beta, rows of 1024.
__launch_bounds__(256)
__global__ void ln_k(const float* __restrict__ resf, const unsigned short* __restrict__ resb,
                     const unsigned short* __restrict__ po,
                     const float* __restrict__ g, const float* __restrict__ be,
                     float* __restrict__ outf, unsigned short* __restrict__ outb) {
  long long row = blockIdx.x;
  int t = threadIdx.x;
  float x0, x1, x2, x3;
  if (resf) {
    float4 va = ((const float4*)(resf + row * H_))[t];
    x0 = va.x; x1 = va.y; x2 = va.z; x3 = va.w;
  } else {
    ushort4 va = ((const ushort4*)(resb + row * H_))[t];
    x0 = bf2f(va.x); x1 = bf2f(va.y); x2 = bf2f(va.z); x3 = bf2f(va.w);
  }
  {
    ushort4 vp = ((const ushort4*)(po + row * H_))[t];
    x0 += bf2f(vp.x); x1 += bf2f(vp.y); x2 += bf2f(vp.z); x3 += bf2f(vp.w);
  }
  float s = x0 + x1 + x2 + x3;
  float q = x0 * x0 + x1 * x1 + x2 * x2 + x3 * x3;
#pragma unroll
  for (int m = 1; m < 64; m <<= 1) { s += __shfl_xor(s, m, 64); q += __shfl_xor(q, m, 64); }
  __shared__ float ssum[4], ssq[4];
  int w = t >> 6, lane = t & 63;
  if (lane == 0) { ssum[w] = s; ssq[w] = q; }
  __syncthreads();
  s = ssum[0] + ssum[1] + ssum[2] + ssum[3];
  q = ssq[0] + ssq[1] + ssq[2] + ssq[3];
  float mean = s * (1.0f / H_);
  float var = q * (1.0f / H_) - mean * mean;
  float rstd = rsqrtf(var + 1e-5f);
  float4 vg = ((const float4*)g)[t];
  float4 vbe = ((const float4*)be)[t];
  float o0 = (x0 - mean) * rstd * vg.x + vbe.x;
  float o1 = (x1 - mean) * rstd * vg.y + vbe.y;
  float o2 = (x2 - mean) * rstd * vg.z + vbe.z;
  float o3 = (x3 - mean) * rstd * vg.w + vbe.w;
  if (outf) {
    float4 o; o.x = o0; o.y = o1; o.z = o2; o.w = o3;
    ((float4*)(outf + row * H_))[t] = o;
  }
  if (outb) {
    ushort4 ob; ob.x = f2b(o0); ob.y = f2b(o1); ob.z = f2b(o2); ob.w = f2b(o3);
    ((ushort4*)(outb + row * H_))[t] = ob;
  }
}

extern "C" void kernel_launch(void* const* d_in, const int* in_sizes, int n_in,
                              void* d_out, int out_size, void* d_ws, size_t ws_size,
                              hipStream_t stream) {
  (void)in_sizes; (void)n_in; (void)out_size; (void)ws_size;
  const float* x      = (const float*)d_in[0];
  const float* enc    = (const float*)d_in[1];
  const float* sa_w[4] = {(const float*)d_in[2], (const float*)d_in[4], (const float*)d_in[6], (const float*)d_in[8]};
  const float* sa_b[4] = {(const float*)d_in[3], (const float*)d_in[5], (const float*)d_in[7], (const float*)d_in[9]};
  const float* sa_pj  = (const float*)d_in[10];
  const float* ca_w[4] = {(const float*)d_in[11], (const float*)d_in[13], (const float*)d_in[15], (const float*)d_in[17]};
  const float* ca_b[4] = {(const float*)d_in[12], (const float*)d_in[14], (const float*)d_in[16], (const float*)d_in[18]};
  const float* ca_pj  = (const float*)d_in[19];
  const float* ff_w1  = (const float*)d_in[20];
  const float* ff_b1  = (const float*)d_in[21];
  const float* ff_w2  = (const float*)d_in[22];
  const float* ff_b2  = (const float*)d_in[23];
  const float* ln1_g  = (const float*)d_in[24];
  const float* ln1_b  = (const float*)d_in[25];
  const float* ln2_g  = (const float*)d_in[26];
  const float* ln2_b  = (const float*)d_in[27];
  const float* ln3_g  = (const float*)d_in[28];
  const float* ln3_b  = (const float*)d_in[29];

  float* ws = (float*)d_ws;
  unsigned short* XB = (unsigned short*)(ws);                 // [16384][1024] bf16
  unsigned short* EB = (unsigned short*)(ws + 8388608LL);     // enc bf16 / AO / ffT
  unsigned short* QKVb = (unsigned short*)(ws + 16777216LL);  // [16384][3072] bf16
  unsigned short* PO = (unsigned short*)(ws + 41943040LL);    // [16384][1024] bf16
  float* ctxP = ws + 41943040LL;                               // ALIAS of PO
  unsigned short* MID2 = QKVb;                                 // FFN mid chunk [8192][4096]
  unsigned short* FO2 = PO;                                    // FFN out chunk [8192][1024]
  unsigned short* WTph = (unsigned short*)(ws + 52428800LL);  // 4 x [1024][1024] bf16
  unsigned short* pjB = (unsigned short*)(ws + 54525952LL);   // 2 x [256][64] bf16
  float* ksumP = ws + 54542336LL;                              // [64][8][256] f32
  float* ksumF = ws + 54673408LL;                              // [64][256] f32
  unsigned short* ctxbf = (unsigned short*)(ws + 55607296LL); // [64][16384] bf16
  float* biasC = ws + 56131584LL;                              // [3072] f32

  unsigned short* ff1T = EB;
  unsigned short* ff2T = EB + 4194304LL;
  unsigned short* pjB_sa = pjB, *pjB_ca = pjB + 16384;

  dim3 blk(256, 1, 1);
  const int LDQ = 3072;

  projB_cvt2<<<dim3(128), blk, 0, stream>>>(sa_pj, ca_pj, pjB);
  cvt_bf16<<<dim3(2048), blk, 0, stream>>>(x, XB, 16777216LL);

  auto attn_core = [&](const unsigned short* pj, const float* wo_bias) {
    ctxksum_mfma<<<dim3(8, 1, 64), blk, 0, stream>>>(QKVb, pj, ksumP, ctxP);
    ctx_fin<<<dim3(64), blk, 0, stream>>>(ctxP, ksumP, ctxbf, ksumF);
    ao_fused<<<dim3(64, 1, 64), blk, 0, stream>>>(QKVb, pj, ksumF, ctxbf, EB);
    gemm_mfma<0><<<dim3(8, 128), blk, 0, stream>>>(EB, H_, WTph + 3145728, wo_bias, PO, H_, H_);
  };

  // ---- self-attention ----
  wt_cvt4<<<dim3(32, 32, 4), blk, 0, stream>>>(sa_w[0], sa_w[1], sa_w[2], sa_w[3], WTph);
  bias_cat<<<dim3(12), blk, 0, stream>>>(sa_b[0], sa_b[1], sa_b[2], biasC);
  gemm_mfma<0><<<dim3(24, 128), blk, 0, stream>>>(XB, H_, WTph, biasC, QKVb, LDQ, H_);
  attn_core(pjB_sa, sa_b[3]);
  ln_k<<<dim3(16384), blk, 0, stream>>>(x, nullptr, PO, ln1_g, ln1_b, nullptr, XB);

  // ---- cross-attention ----
  cvt_bf16<<<dim3(2048), blk, 0, stream>>>(enc, EB, 16777216LL);
  wt_cvt4<<<dim3(32, 32, 4), blk, 0, stream>>>(ca_w[0], ca_w[1], ca_w[2], ca_w[3], WTph);
  bias_cat<<<dim3(8), blk, 0, stream>>>(ca_b[1], ca_b[2], nullptr, biasC);
  gemm_mfma<0><<<dim3(8, 128), blk, 0, stream>>>(XB, H_, WTph, ca_b[0], QKVb, LDQ, H_);
  gemm_mfma<0><<<dim3(16, 128), blk, 0, stream>>>(EB, H_, WTph + 1048576, biasC, QKVb + 1024, LDQ, H_);
  attn_core(pjB_ca, ca_b[3]);
  ln_k<<<dim3(16384), blk, 0, stream>>>(nullptr, XB, PO, ln2_g, ln2_b, nullptr, XB);

  // ---- FFN: 2 chunks of 8192 rows ----
  wt_cvt<<<dim3(128, 32), blk, 0, stream>>>(ff_w1, ff1T, H_, 4096);
  wt_cvt<<<dim3(32, 128), blk, 0, stream>>>(ff_w2, ff2T, 4096, H_);
  for (int c = 0; c < 2; ++c) {
    const long long co = (long long)c * 8192 * H_;
    gemm_mfma<1><<<dim3(32, 64), blk, 0, stream>>>(XB + co, H_, ff1T, ff_b1, MID2, 4096, H_);
    gemm_mfma<0><<<dim3(8, 64), blk, 0, stream>>>(MID2, 4096, ff2T, ff_b2, FO2, H_, 4096);
    ln_k<<<dim3(8192), blk, 0, stream>>>(nullptr, XB + co, FO2, ln3_g, ln3_b,
                                         (float*)d_out + co, nullptr);
  }
}